// Round 7
// baseline (27.797 us; speedup 1.0000x reference)
//
#include <hip/hip_runtime.h>
#include <hip/hip_bf16.h>
#include <float.h>

#define NGROUPS 128
#define CPAD    16    // counts padded to one 64B cache line per group
#define SLOT    512   // per-group slot cap; group sizes ~128±11 (512 = 34 sigma)

// ws layout: [0, 8KB) padded counts int[128*16] | [8KB, 8KB+128*512*16B) gx float4 slots
//
// memset(8KB) -> kde_scatter (O(M): 1 thread/point, padded global atomic for
// slot position, float4 write) -> kde_select (two points per wave: each
// 32-lane half owns a point; NR=8 register candidates, static sort network,
// shared DPP pop loop; exact 64-lane fallback for c>256).
// Determinism: slot order races, but each point's candidate MULTISET is
// identical every run and k-th-smallest is a set function.

__global__ __launch_bounds__(64) void kde_scatter(
        const int* __restrict__ idx,
        const float* __restrict__ x,
        int M,
        int* __restrict__ counts,
        float4* __restrict__ gx) {
    const int i = blockIdx.x * 64 + threadIdx.x;
    if (i >= M) return;
    const int g = idx[i];
    float4 v;
    v.x = x[3 * i + 0];
    v.y = x[3 * i + 1];
    v.z = x[3 * i + 2];
    v.w = 0.0f;
    const int p = atomicAdd(&counts[g * CPAD], 1);
    if (p < SLOT) gx[(size_t)g * SLOT + p] = v;
}

// DPP min step: shifted-in lanes read old=FLT_MAX (bound_ctrl false)
#define DPP_MIN_STEP(v, CTRL)                                                  \
    v = fminf(v, __int_as_float(__builtin_amdgcn_update_dpp(                   \
            0x7f7fffff /*FLT_MAX bits*/, __float_as_int(v), CTRL, 0xf, 0xf,    \
            false)))

#define CSWAP(arr, a, b)                                                       \
    do { float lo_ = fminf(arr[a], arr[b]); float hi_ = fmaxf(arr[a], arr[b]); \
         arr[a] = lo_; arr[b] = hi_; } while (0)

#define SORT8(arr)                                                             \
    do {                                                                       \
        CSWAP(arr,0,1); CSWAP(arr,2,3); CSWAP(arr,4,5); CSWAP(arr,6,7);        \
        CSWAP(arr,0,2); CSWAP(arr,1,3); CSWAP(arr,4,6); CSWAP(arr,5,7);        \
        CSWAP(arr,1,2); CSWAP(arr,5,6);                                        \
        CSWAP(arr,0,4); CSWAP(arr,1,5); CSWAP(arr,2,6); CSWAP(arr,3,7);        \
        CSWAP(arr,2,4); CSWAP(arr,3,5);                                        \
        CSWAP(arr,1,2); CSWAP(arr,3,4); CSWAP(arr,5,6);                        \
    } while (0)

// exact 64-lane fallback (proven r6, absmax 0): full-wave NR=8, covers c<=512
__device__ __forceinline__ float kth_smallest_full(
        const float4* __restrict__ slot, int c, int K,
        float xm, float ym, float zm, int lane) {
    float r[8];
#pragma unroll
    for (int k = 0; k < 8; ++k) {
        const int j = lane + 64 * k;          // < 512 = SLOT: load in-bounds
        const float4 v = slot[j];
        const float dx = v.x - xm;
        const float dy = v.y - ym;
        const float dz = v.z - zm;
        const float d2 = dx * dx + dy * dy + dz * dz;
        r[k] = (j < c) ? d2 : FLT_MAX;
    }
    SORT8(r);
    float ans = 0.0f;
    int cnt = 0;
    for (int it = 0; it < K; ++it) {
        float v = r[0];
        DPP_MIN_STEP(v, 0x111);  // row_shr:1
        DPP_MIN_STEP(v, 0x112);  // row_shr:2
        DPP_MIN_STEP(v, 0x114);  // row_shr:4
        DPP_MIN_STEP(v, 0x118);  // row_shr:8
        DPP_MIN_STEP(v, 0x142);  // row_bcast:15
        DPP_MIN_STEP(v, 0x143);  // row_bcast:31
        const float m = __int_as_float(
            __builtin_amdgcn_readlane(__float_as_int(v), 63));
        ans = m;
        const bool cond = (r[0] == m);
        cnt += (int)__popcll(__ballot(cond));
#pragma unroll
        for (int k = 0; k < 7; ++k) r[k] = cond ? r[k + 1] : r[k];
        r[7] = cond ? FLT_MAX : r[7];
        if (cnt >= K) break;
    }
    return ans;
}

__global__ __launch_bounds__(256) void kde_select(
        const float* __restrict__ x,
        const int* __restrict__ idx,
        const float4* __restrict__ gx,
        const int* __restrict__ counts,
        const int* __restrict__ Kptr,
        int M,
        float* __restrict__ out) {
    const int w    = blockIdx.x * 4 + (threadIdx.x >> 6);  // wave id
    const int lane = threadIdx.x & 63;
    const int half = lane >> 5;
    const int l32  = lane & 31;
    const int widLo = 2 * w, widHi = 2 * w + 1;
    if (widLo >= M) return;  // M even -> widHi valid too
    const int K = Kptr[0];

    const int gLo = idx[widLo], gHi = idx[widHi];
    int cLo = counts[gLo * CPAD];  cLo = (cLo < SLOT) ? cLo : SLOT;
    int cHi = counts[gHi * CPAD];  cHi = (cHi < SLOT) ? cHi : SLOT;

    const float xLo = x[3 * widLo + 0], yLo = x[3 * widLo + 1], zLo = x[3 * widLo + 2];
    const float xHi = x[3 * widHi + 0], yHi = x[3 * widHi + 1], zHi = x[3 * widHi + 2];

    float ansLo, ansHi;
    if (cLo <= 256 && cHi <= 256) {
        // ---- fast path: each 32-lane half owns one point, NR=8 ----
        const float4* __restrict__ slot = gx + (size_t)(half ? gHi : gLo) * SLOT;
        const int   c  = half ? cHi : cLo;
        const float xm = half ? xHi : xLo;
        const float ym = half ? yHi : yLo;
        const float zm = half ? zHi : zLo;

        float r[8];
#pragma unroll
        for (int k = 0; k < 8; ++k) {
            const int j = l32 + 32 * k;       // < 256 <= SLOT: in-bounds
            const float4 v = slot[j];
            const float dx = v.x - xm;
            const float dy = v.y - ym;
            const float dz = v.z - zm;
            const float d2 = dx * dx + dy * dy + dz * dz;
            r[k] = (j < c) ? d2 : FLT_MAX;
        }
        SORT8(r);

        // shared pop loop: 5-step DPP reduce -> lane31 = min of lanes 0..31,
        // lane63 = min of lanes 32..63 (verified row_bcast semantics).
        int cntL = 0, cntH = 0;
        ansLo = 0.0f; ansHi = 0.0f;
        for (int it = 0; it < K; ++it) {
            float v = r[0];
            DPP_MIN_STEP(v, 0x111);  // row_shr:1
            DPP_MIN_STEP(v, 0x112);  // row_shr:2
            DPP_MIN_STEP(v, 0x114);  // row_shr:4
            DPP_MIN_STEP(v, 0x118);  // row_shr:8
            DPP_MIN_STEP(v, 0x142);  // row_bcast:15
            const float sLo = __int_as_float(
                __builtin_amdgcn_readlane(__float_as_int(v), 31));
            const float sHi = __int_as_float(
                __builtin_amdgcn_readlane(__float_as_int(v), 63));
            const bool aLo = (cntL < K), aHi = (cntH < K);
            if (aLo) ansLo = sLo;
            if (aHi) ansHi = sHi;
            const float m   = half ? sHi : sLo;
            const bool  act = half ? aHi : aLo;
            const bool cond = act && (r[0] == m);
            const unsigned long long bal = __ballot(cond);
            cntL += __popc((unsigned)bal);
            cntH += __popc((unsigned)(bal >> 32));
#pragma unroll
            for (int k = 0; k < 7; ++k) r[k] = cond ? r[k + 1] : r[k];
            r[7] = cond ? FLT_MAX : r[7];
            if (cntL >= K && cntH >= K) break;
        }
    } else {
        // ---- exact fallback for c in (256, 512]: full wave, sequential ----
        ansLo = kth_smallest_full(gx + (size_t)gLo * SLOT, cLo, K, xLo, yLo, zLo, lane);
        ansHi = kth_smallest_full(gx + (size_t)gHi * SLOT, cHi, K, xHi, yHi, zHi, lane);
    }

    if (lane == 0) {
        // dim = NI-1 = 2: volume = pi*r^2 = pi*ans (ans is squared distance).
        const float pi = 3.14159265358979323846f;
        float2 o;
        o.x = (cLo < K) ? (1.0f / (float)cLo) : (pi * ansLo / (float)(K - 1));
        o.y = (cHi < K) ? (1.0f / (float)cHi) : (pi * ansHi / (float)(K - 1));
        *(float2*)&out[widLo] = o;   // widLo even -> 8B aligned
    }
}

extern "C" void kernel_launch(void* const* d_in, const int* in_sizes, int n_in,
                              void* d_out, int out_size, void* d_ws, size_t ws_size,
                              hipStream_t stream) {
    const float* x   = (const float*)d_in[0];
    const int*   idx = (const int*)d_in[1];
    const int*   Kp  = (const int*)d_in[2];
    float* out = (float*)d_out;

    const int M = in_sizes[1];  // 16384

    int*    counts = (int*)d_ws;
    float4* gx     = (float4*)((char*)d_ws + NGROUPS * CPAD * sizeof(int));

    hipMemsetAsync(counts, 0, NGROUPS * CPAD * sizeof(int), stream);

    const int sblocks = (M + 63) / 64;
    kde_scatter<<<sblocks, 64, 0, stream>>>(idx, x, M, counts, gx);

    const int blocks = (M + 7) / 8;  // 4 waves x 2 points per 256-thread block
    kde_select<<<blocks, 256, 0, stream>>>(x, idx, gx, counts, Kp, M, out);
}